// Round 14
// baseline (529.965 us; speedup 1.0000x reference)
//
#include <hip/hip_runtime.h>
#include <math.h>

#define NN 20000
#define NE 200000
#define TT 13
#define NBLK 79   // ceil(NN/256)

typedef short bf16x8 __attribute__((ext_vector_type(8)));
typedef float f32x4 __attribute__((ext_vector_type(4)));

__device__ inline unsigned short f2bf(float f){
  union{float f; unsigned u;} v; v.f = f;
  unsigned r = v.u + 0x7fffu + ((v.u >> 16) & 1u);
  return (unsigned short)(r >> 16);
}
__device__ inline float bf2f(unsigned short h){
  union{unsigned u; float f;} v; v.u = ((unsigned)h) << 16; return v.f;
}
__device__ inline float fsig(float x){ return __builtin_amdgcn_rcpf(1.f + __expf(-x)); }
__device__ inline float ftanh(float x){ return 2.f*__builtin_amdgcn_rcpf(1.f + __expf(-2.f*x)) - 1.f; }

// ---------------- fused prep: all weight re-layouts in one dispatch ----------------
__device__ inline void d_prepw2(const float* W0, const float* W1, const float* b,
    unsigned short* Wt, float* bPerm, int F, int Kp, int T, int idx){
  if(idx >= F*Kp) return;
  int o = idx / Kp, k = idx - o*Kp;
  int to = o >> 5, co = o & 31; int fout = co*T + to;
  int ki = (k < F) ? k : k - F;
  int ti = ki >> 5, ci = ki & 31; int fin = ci*T + ti;
  float v = (k < F) ? W0[fin*F + fout] : W1[fin*F + fout];
  Wt[idx] = f2bf(v);
  if(k == 0) bPerm[o] = b[fout];
}
__device__ inline void d_prep2(const float* sW, const float* sb,
    unsigned short* Bwt, float* b2, int idx){
  if(idx >= 65536) return;
  int sOut = idx >> 8; int ic = idx & 255; int i = ic >> 5; int c = ic & 31;
  Bwt[idx] = f2bf(sW[i*8192 + sOut*32 + c]);
  if(idx < 256){
    float acc = 0.f;
    for(int ll = 0; ll < 8; ll++) acc += sb[ll*256 + idx];
    b2[idx] = acc;
  }
}
__device__ inline void d_comb(const float* e1W, const float* e1b,
    const float* e2W, const float* e2b, float* Wc, float* bc, int idx){
  if(idx >= 12*256) return;
  int k = idx >> 8, c = idx & 255;
  float acc = 0.f;
  for(int o = 0; o < 512; o++) acc += e2W[k*512+o]*e1W[o*256+c];
  Wc[idx] = acc;
  if(c == 0){
    float b = e2b[k];
    for(int o = 0; o < 512; o++) b += e2W[k*512+o]*e1b[o];
    bc[k] = b;
  }
}
__device__ inline void d_prepg(const float* fW, const float* fb,
    const float* gW, const float* gb, unsigned short* Wfrag, float* Bfrag, int idx){
  if(idx < 8*8*64*8){
    int j = idx & 7; int lane = (idx >> 3) & 63; int chunk = (idx >> 9) & 7; int layer = idx >> 12;
    int fg = chunk >> 2; int q = (chunk >> 1) & 1; int i = chunk & 1;
    int quad = lane >> 4, tcol = lane & 15;
    int cout = 16*i + tcol, cin = quad*8 + j;
    const float* W = fg ? gW : fW;
    Wfrag[idx] = f2bf(W[layer*2048 + cout*64 + cin*2 + q]);
  }
  if(idx < 8*64*4){
    int r = idx & 3; int lane = (idx >> 2) & 63; int layer = idx >> 8;
    int tcol = lane & 15;
    float v;
    if(r == 0)      v = fb[layer*32 + tcol];
    else if(r == 1) v = fb[layer*32 + 16 + tcol];
    else if(r == 2) v = gb[layer*32 + tcol];
    else            v = gb[layer*32 + 16 + tcol];
    Bfrag[idx] = v;
  }
}
__global__ __launch_bounds__(256) void k_prepall(
    const float* g0W0, const float* g0W1, const float* g0b,
    const float* g1W0, const float* g1W1, const float* g1b,
    const float* sW, const float* sb,
    const float* e1W, const float* e1b, const float* e2W, const float* e2b,
    const float* fW, const float* fb, const float* gW, const float* gb,
    unsigned short* Wt0, float* bP0, unsigned short* Wt1, float* bP1,
    unsigned short* Bwt, float* bias2, float* Wc, float* bc,
    unsigned short* Wfrag, float* Bfrag){
  int b = blockIdx.x, t = threadIdx.x;
  if(b < 1152)       d_prepw2(g0W0, g0W1, g0b, Wt0, bP0, 384, 768, 12, b*256 + t);
  else if(b < 1440)  d_prepw2(g1W0, g1W1, g1b, Wt1, bP1, 192, 384, 6, (b-1152)*256 + t);
  else if(b < 1696)  d_prep2(sW, sb, Bwt, bias2, (b-1440)*256 + t);
  else if(b < 1708)  d_comb(e1W, e1b, e2W, e2b, Wc, bc, (b-1696)*256 + t);
  else               d_prepg(fW, fb, gW, gb, Wfrag, Bfrag, (b-1708)*256 + t);
}

// ---------------- edge prep ----------------
__global__ __launch_bounds__(256) void k_deg(const int* __restrict__ ei,
    const float* __restrict__ ea, float* __restrict__ deg){
  int e = blockIdx.x*256 + threadIdx.x;
  if(e >= NE) return;
  int r = ei[e], c = ei[NE+e];
  float w = (r==c) ? 0.f : ea[e];
  if(w != 0.f) atomicAdd(&deg[r], w);
}

__global__ __launch_bounds__(256) void k_normcount(const int* __restrict__ ei,
    const float* __restrict__ ea, const float* __restrict__ deg,
    float* __restrict__ nrm, int* __restrict__ cnt){
  int e = blockIdx.x*256 + threadIdx.x;
  if(e >= NE) return;
  int r = ei[e], c = ei[NE+e];
  float w = (r==c) ? 0.f : ea[e];
  float dr = deg[r], dc = deg[c];
  float ir = (dr > 0.f) ? rsqrtf(dr) : 0.f;
  float ic = (dc > 0.f) ? rsqrtf(dc) : 0.f;
  float nv = ir*w*ic;
  nrm[e] = nv;
  if(nv != 0.f) atomicAdd(&cnt[c], 1);
}

__global__ __launch_bounds__(256) void k_scanA(const int* __restrict__ cnt, int* __restrict__ bsum){
  int i = blockIdx.x*256 + threadIdx.x;
  int l = threadIdx.x & 63, w = threadIdx.x >> 6;
  int v = (i < NN) ? cnt[i] : 0;
#pragma unroll
  for(int off = 1; off < 64; off <<= 1) v += __shfl_xor(v, off);
  __shared__ int ws4[4];
  if(l == 0) ws4[w] = v;
  __syncthreads();
  if(threadIdx.x == 0) bsum[blockIdx.x] = ws4[0]+ws4[1]+ws4[2]+ws4[3];
}

__global__ __launch_bounds__(256) void k_scanC(const int* __restrict__ cnt,
    const int* __restrict__ bsum, int* __restrict__ rowptr, int* __restrict__ woff){
  __shared__ int sb[128];
  int t = threadIdx.x;
  if(t < 128) sb[t] = (t < NBLK) ? bsum[t] : 0;
  __syncthreads();
  for(int off = 1; off < 128; off <<= 1){
    int u = 0;
    if(t < 128 && t >= off) u = sb[t-off];
    __syncthreads();
    if(t < 128) sb[t] += u;
    __syncthreads();
  }
  int i = blockIdx.x*256 + t;
  int l = t & 63, w = t >> 6;
  int v = (i < NN) ? cnt[i] : 0;
  int x = v;
#pragma unroll
  for(int off = 1; off < 64; off <<= 1){
    int u = __shfl_up(x, off);
    if(l >= off) x += u;
  }
  __shared__ int wt[4];
  if(l == 63) wt[w] = x;
  __syncthreads();
  int wo = 0;
  for(int k = 0; k < w; k++) wo += wt[k];
  int bb = (blockIdx.x > 0) ? sb[blockIdx.x-1] : 0;
  int excl = bb + wo + x - v;
  if(i < NN){ rowptr[i] = excl; woff[i] = excl; }
  if(i == 0) rowptr[NN] = sb[NBLK-1];
}

__global__ __launch_bounds__(256) void k_place(const float* __restrict__ nrm,
    const int* __restrict__ ei, int* __restrict__ woff,
    int* __restrict__ rowArr, float* __restrict__ nrmArr){
  int e = blockIdx.x*256 + threadIdx.x;
  if(e >= NE) return;
  float nv = nrm[e];
  if(nv == 0.f) return;
  int c = ei[NE+e];
  int pos = atomicAdd(&woff[c], 1);
  rowArr[pos] = ei[e];
  nrmArr[pos] = nv;
}

// ---------------- gather SpMM with INLINE BN ----------------
__global__ void k_gather3(const unsigned short* __restrict__ h, int F, int F2,
    const float* __restrict__ bnstats, float cntInv,
    const int* __restrict__ rowArr, const float* __restrict__ nrmArr,
    const int* __restrict__ rowptr, unsigned short* __restrict__ tx1){
  __shared__ float bnm[32], bnv[32];
  __shared__ int srow[64];
  __shared__ float snrm[64];
  int tid = threadIdx.x;
  if(tid < 32){
    float s = 0.f, s2 = 0.f;
#pragma unroll
    for(int b = 0; b < 16; b++){ s += bnstats[b*64 + tid]; s2 += bnstats[b*64 + 32 + tid]; }
    float m = s*cntInv; float var = s2*cntInv - m*m;
    bnm[tid] = m; bnv[tid] = rsqrtf(var + 1e-5f);
  }
  __syncthreads();
  int node = blockIdx.x;
  int f2 = tid;
  int c0 = (2*f2) & 31;
  float m0 = bnm[c0], i0 = bnv[c0], m1 = bnm[c0+1], i1 = bnv[c0+1];
  int beg = rowptr[node], end = rowptr[node+1];
  float a0 = 0.f, a1 = 0.f;
  for(int base = beg; base < end; base += 64){
    int m = end - base; if(m > 64) m = 64;
    __syncthreads();
    if(tid < m){ srow[tid] = rowArr[base+tid]; snrm[tid] = nrmArr[base+tid]; }
    __syncthreads();
    if(f2 < F2){
      for(int j = 0; j < m; j++){
        unsigned u = *(const unsigned*)(h + (size_t)srow[j]*F + 2*f2);
        float nv = snrm[j];
        a0 += nv*(bf2f((unsigned short)(u & 0xffffu)) - m0)*i0;
        a1 += nv*(bf2f((unsigned short)(u >> 16)) - m1)*i1;
      }
    }
  }
  if(f2 < F2){
    unsigned outw = (unsigned)f2bf(-a0) | ((unsigned)f2bf(-a1) << 16);
    *(unsigned*)(tx1 + (size_t)node*F + 2*f2) = outw;
  }
}

// ---------------- GCN GEMM with INLINE BN; grid = m-tiles only, n-loop INSIDE the
// ---------------- block so A m-tile re-reads hit this block's own XCD L2 ----------------
template<bool BOUT>
__global__ __launch_bounds__(256) void k_gemm_gcn(
    const unsigned short* __restrict__ hSrc, const unsigned short* __restrict__ tx1,
    const unsigned short* __restrict__ Bt, const float* __restrict__ bias,
    const float* __restrict__ bnstats, float cntInv,
    void* __restrict__ Cv, int M, int N, int F){
  constexpr int LR = 40;
  __shared__ unsigned short As[128*LR];
  __shared__ unsigned short Bs[64*LR];
  __shared__ float bnm[32], bnv[32];
  int tid = threadIdx.x;
  if(tid < 32){
    float s = 0.f, s2 = 0.f;
#pragma unroll
    for(int b = 0; b < 16; b++){ s += bnstats[b*64 + tid]; s2 += bnstats[b*64 + 32 + tid]; }
    float m = s*cntInv; float var = s2*cntInv - m*m;
    bnm[tid] = m; bnv[tid] = rsqrtf(var + 1e-5f);
  }
  __syncthreads();
  int w = tid >> 6, l = tid & 63, quad = l >> 4, tcol = l & 15;
  int m0 = blockIdx.x*128;
  int rw = (w & 1)*64, cw = (w >> 1)*32;
  int sr = tid >> 2, sc = (tid & 3)*8;
  float am[8], ai[8];
#pragma unroll
  for(int j = 0; j < 8; j++){ am[j] = bnm[sc+j]; ai[j] = bnv[sc+j]; }
  int K = 2*F;
  for(int n0 = 0; n0 < N; n0 += 64){
    f32x4 acc[4][2];
#pragma unroll
    for(int i = 0; i < 4; i++)
#pragma unroll
      for(int j = 0; j < 2; j++) acc[i][j] = (f32x4){0.f,0.f,0.f,0.f};
    for(int k0 = 0; k0 < K; k0 += 32){
      uint4 a0r, a1r;
      if(k0 < F){
        uint4 r0 = *(const uint4*)(hSrc + (size_t)(m0 + sr)*F + k0 + sc);
        uint4 r1 = *(const uint4*)(hSrc + (size_t)(m0 + 64 + sr)*F + k0 + sc);
        unsigned short o0[8], o1[8];
        const unsigned short* p0 = (const unsigned short*)&r0;
        const unsigned short* p1 = (const unsigned short*)&r1;
#pragma unroll
        for(int j = 0; j < 8; j++){
          o0[j] = f2bf((bf2f(p0[j]) - am[j])*ai[j]);
          o1[j] = f2bf((bf2f(p1[j]) - am[j])*ai[j]);
        }
        a0r = *(const uint4*)o0; a1r = *(const uint4*)o1;
      } else {
        a0r = *(const uint4*)(tx1 + (size_t)(m0 + sr)*F + (k0-F) + sc);
        a1r = *(const uint4*)(tx1 + (size_t)(m0 + 64 + sr)*F + (k0-F) + sc);
      }
      uint4 b0 = *(const uint4*)(Bt + (size_t)(n0 + sr)*K + k0 + sc);
      __syncthreads();
      *(uint4*)(As + sr*LR + sc) = a0r;
      *(uint4*)(As + (64+sr)*LR + sc) = a1r;
      *(uint4*)(Bs + sr*LR + sc) = b0;
      __syncthreads();
      bf16x8 av[4], bv[2];
#pragma unroll
      for(int i = 0; i < 4; i++) av[i] = *(const bf16x8*)(As + (rw + 16*i + tcol)*LR + quad*8);
#pragma unroll
      for(int j = 0; j < 2; j++) bv[j] = *(const bf16x8*)(Bs + (cw + 16*j + tcol)*LR + quad*8);
#pragma unroll
      for(int i = 0; i < 4; i++)
#pragma unroll
        for(int j = 0; j < 2; j++)
          acc[i][j] = __builtin_amdgcn_mfma_f32_16x16x32_bf16(av[i], bv[j], acc[i][j], 0, 0, 0);
    }
#pragma unroll
    for(int i = 0; i < 4; i++){
#pragma unroll
      for(int j = 0; j < 2; j++){
        int col = n0 + cw + 16*j + tcol;
        float bb = bias[col];
#pragma unroll
        for(int r = 0; r < 4; r++){
          int row = m0 + rw + 16*i + quad*4 + r;
          if(row < M){
            float o = acc[i][j][r] + bb;
            if(BOUT) ((unsigned short*)Cv)[(size_t)row*N + col] = f2bf(o);
            else ((float*)Cv)[(size_t)row*N + col] = o;
          }
        }
      }
    }
  }
}

// ---------------- FUSED L0: instnorm + start conv + L0 -> hB + gl + stats ----------------
__global__ __launch_bounds__(256,3) void k_fused0nb(
    const float* __restrict__ x, const float* __restrict__ startW, const float* __restrict__ startb,
    const unsigned short* __restrict__ Wfrag, const float* __restrict__ Bfrag,
    unsigned short* __restrict__ glcat, unsigned short* __restrict__ hOut,
    float* __restrict__ stdev, float* __restrict__ means,
    float* __restrict__ bnstats){
  __shared__ float xs[40][14];
  __shared__ float swl[32], sbl[32];
  __shared__ unsigned short bufB[40*12*40];
  __shared__ float bnred[64];
  int tid = threadIdx.x;
  int w = tid >> 6, l = tid & 63, quad = l >> 4, tcol = l & 15;
  int base = blockIdx.x*40;
  for(int j = tid; j < 520; j += 256){ int n = j/13, t = j - n*13; xs[n][t] = x[(size_t)(base+n)*13 + t]; }
  if(tid < 32){ swl[tid] = startW[tid]; sbl[tid] = startb[tid]; }
  if(tid < 64) bnred[tid] = 0.f;
  __syncthreads();
  if(tid < 40){
    float s = 0.f;
#pragma unroll
    for(int t = 0; t < 13; t++) s += xs[tid][t];
    float m = s*(1.0f/13.f);
    float s2 = 0.f;
#pragma unroll
    for(int t = 0; t < 13; t++){ float d = xs[tid][t]-m; s2 += d*d; }
    float sd = sqrtf(s2*(1.0f/13.f) + 1e-5f);
    float inv = 1.0f/sd;
    means[base+tid] = m; stdev[base+tid] = sd;
#pragma unroll
    for(int t = 0; t < 13; t++) xs[tid][t] = (xs[tid][t]-m)*inv;
  }
  __syncthreads();
  bf16x8 bwf[2][2], bwg[2][2];
#pragma unroll
  for(int q = 0; q < 2; q++)
#pragma unroll
    for(int i = 0; i < 2; i++){
      bwf[q][i] = *(const bf16x8*)(Wfrag + ((q*2+i)*64 + l)*8);
      bwg[q][i] = *(const bf16x8*)(Wfrag + ((4 + q*2+i)*64 + l)*8);
    }
  float4 bv4 = *(const float4*)(Bfrag + l*4);
  float fbv[2] = {bv4.x, bv4.y}, gbv[2] = {bv4.z, bv4.w};
  float sw8[8], sb8[8], swc[2], sbc[2];
#pragma unroll
  for(int j = 0; j < 8; j++){ sw8[j] = swl[quad*8+j]; sb8[j] = sbl[quad*8+j]; }
#pragma unroll
  for(int i = 0; i < 2; i++){ swc[i] = swl[16*i+tcol]; sbc[i] = sbl[16*i+tcol]; }
  float sAc[2] = {0.f,0.f}, s2Ac[2] = {0.f,0.f};
  int tr = (tcol < 12) ? tcol : 0;
  for(int p = 0; p < 5; p++){
    int slA = w*10 + 2*p, slB = slA + 1;
    float x0A = xs[slA][tr], x1A = xs[slA][tr+1];
    float x0B = xs[slB][tr], x1B = xs[slB][tr+1];
    bf16x8 aA0, aA1, aB0, aB1;
#pragma unroll
    for(int j = 0; j < 8; j++){
      aA0[j] = (short)f2bf(sw8[j]*x0A + sb8[j]);
      aA1[j] = (short)f2bf(sw8[j]*x1A + sb8[j]);
      aB0[j] = (short)f2bf(sw8[j]*x0B + sb8[j]);
      aB1[j] = (short)f2bf(sw8[j]*x1B + sb8[j]);
    }
    f32x4 afA[2], agA[2], afB[2], agB[2];
#pragma unroll
    for(int i = 0; i < 2; i++){
      afA[i] = (f32x4){0.f,0.f,0.f,0.f}; agA[i] = afA[i];
      afB[i] = afA[i]; agB[i] = afA[i];
    }
#pragma unroll
    for(int i = 0; i < 2; i++){
      afA[i] = __builtin_amdgcn_mfma_f32_16x16x32_bf16(aA0, bwf[0][i], afA[i], 0,0,0);
      afB[i] = __builtin_amdgcn_mfma_f32_16x16x32_bf16(aB0, bwf[0][i], afB[i], 0,0,0);
      afA[i] = __builtin_amdgcn_mfma_f32_16x16x32_bf16(aA1, bwf[1][i], afA[i], 0,0,0);
      afB[i] = __builtin_amdgcn_mfma_f32_16x16x32_bf16(aB1, bwf[1][i], afB[i], 0,0,0);
      agA[i] = __builtin_amdgcn_mfma_f32_16x16x32_bf16(aA0, bwg[0][i], agA[i], 0,0,0);
      agB[i] = __builtin_amdgcn_mfma_f32_16x16x32_bf16(aB0, bwg[0][i], agB[i], 0,0,0);
      agA[i] = __builtin_amdgcn_mfma_f32_16x16x32_bf16(aA1, bwg[1][i], agA[i], 0,0,0);
      agB[i] = __builtin_amdgcn_mfma_f32_16x16x32_bf16(aB1, bwg[1][i], agB[i], 0,0,0);
    }
#pragma unroll
    for(int i = 0; i < 2; i++){
      int cout = 16*i + tcol;
#pragma unroll
      for(int r = 0; r < 4; r++){
        int t = quad*4 + r;
        if(t < 12){
          float fA = afA[i][r] + fbv[i], gA = agA[i][r] + gbv[i];
          float fB = afB[i][r] + fbv[i], gB = agB[i][r] + gbv[i];
          float gatA = ftanh(fA)*fsig(gA);
          float gatB = ftanh(fB)*fsig(gB);
          if(t == 11){
            glcat[(size_t)(base+slA)*256 + cout] = f2bf(gatA);
            glcat[(size_t)(base+slB)*256 + cout] = f2bf(gatB);
          }
          float oA = gatA + swc[i]*xs[slA][t+1] + sbc[i];
          float oB = gatB + swc[i]*xs[slB][t+1] + sbc[i];
          bufB[slA*480 + t*40 + cout] = f2bf(oA);
          bufB[slB*480 + t*40 + cout] = f2bf(oB);
          sAc[i] += oA + oB; s2Ac[i] += oA*oA + oB*oB;
        }
      }
    }
  }
#pragma unroll
  for(int i = 0; i < 2; i++){
    sAc[i]  += __shfl_xor(sAc[i], 16);  sAc[i]  += __shfl_xor(sAc[i], 32);
    s2Ac[i] += __shfl_xor(s2Ac[i], 16); s2Ac[i] += __shfl_xor(s2Ac[i], 32);
  }
  if(l < 16){
#pragma unroll
    for(int i = 0; i < 2; i++){
      atomicAdd(&bnred[16*i + l], sAc[i]);
      atomicAdd(&bnred[32 + 16*i + l], s2Ac[i]);
    }
  }
  __syncthreads();
  if(tid < 64) atomicAdd(&bnstats[(blockIdx.x & 15)*64 + tid], bnred[tid]);
  for(int j = tid; j < 40*48; j += 256){
    int s = j/48; int q = j - s*48; int t = q >> 2; int cb = (q & 3)*8;
    *(uint4*)(hOut + (size_t)(base+s)*384 + t*32 + cb) = *(const uint4*)(bufB + s*480 + t*40 + cb);
  }
}

// ---------------- gated conv; wave = 4 contiguous nodes (2 pairs) ----------------
template<int D,int TIN,int TOUT,bool BNIN,bool STATS,bool WRITEH>
__global__ __launch_bounds__(256) void k_gated5(
    const unsigned short* __restrict__ hIn, unsigned short* __restrict__ hOut,
    unsigned short* __restrict__ gl,
    const float* __restrict__ bnIn, float* __restrict__ bnOut,
    const unsigned short* __restrict__ Wfrag, const float* __restrict__ Bfrag,
    int layer, float cntInv){
  constexpr int RS = 40;
  __shared__ unsigned short hs[4][2][TIN*RS];
  __shared__ unsigned short ho[4][2][WRITEH ? TOUT*RS : RS];
  __shared__ float bnm[32], bnv[32];
  __shared__ float bnred[64];
  int tid = threadIdx.x;
  int w = tid >> 6, l = tid & 63, quad = l >> 4, tcol = l & 15;
  if(BNIN && tid < 32){
    float s = 0.f, s2 = 0.f;
#pragma unroll
    for(int b = 0; b < 16; b++){ s += bnIn[b*64 + tid]; s2 += bnIn[b*64 + 32 + tid]; }
    float m = s*cntInv;
    float var = s2*cntInv - m*m;
    bnm[tid] = m; bnv[tid] = rsqrtf(var + 1e-5f);
  }
  if(STATS && tid < 64) bnred[tid] = 0.f;
  __syncthreads();
  float sm[8], sv[8];
  if(BNIN){
    int cb = (l & 3)*8;
#pragma unroll
    for(int j=0;j<8;j++){ sm[j] = bnm[cb+j]; sv[j] = bnv[cb+j]; }
  }
  const unsigned short* wfr = Wfrag + layer*4096;
  bf16x8 bwf[2][2], bwg[2][2];
#pragma unroll
  for(int q=0;q<2;q++)
#pragma unroll
    for(int i=0;i<2;i++){
      bwf[q][i] = *(const bf16x8*)(wfr + ((q*2+i)*64 + l)*8);
      bwg[q][i] = *(const bf16x8*)(wfr + ((4 + q*2+i)*64 + l)*8);
    }
  float4 bv4 = *(const float4*)(Bfrag + layer*256 + l*4);
  float fbv[2] = {bv4.x, bv4.y}, gbv[2] = {bv4.z, bv4.w};

  int tr = (tcol < TOUT) ? tcol : 0;
  unsigned short* hwA = hs[w][0];
  unsigned short* hwB = hs[w][1];
  unsigned short* howA = ho[w][0];
  unsigned short* howB = ho[w][1];
  float sA[2] = {0.f,0.f}, s2A[2] = {0.f,0.f};
  int wid = blockIdx.x*4 + w;
  int base = wid*4;
  bool ldact = (l < TIN*4);
  int ts = l >> 2, cb = (l & 3)*8;
  uint4 vA = {0,0,0,0}, vB = {0,0,0,0};
  if(ldact && base < NN){
    vA = *(const uint4*)(hIn + (size_t)base*TIN*32 + l*8);
    vB = *(const uint4*)(hIn + (size_t)(base+1)*TIN*32 + l*8);
  }
  for(int p = 0; p < 2; p++){
    int nA = base + 2*p;
    if(nA >= NN) break;
    int nB = nA + 1;
    if(ldact){
      if(BNIN){
        unsigned short tA[8], tB[8];
        const unsigned short* uA = (const unsigned short*)&vA;
        const unsigned short* uB = (const unsigned short*)&vB;
#pragma unroll
        for(int j=0;j<8;j++){
          tA[j] = f2bf((bf2f(uA[j]) - sm[j])*sv[j]);
          tB[j] = f2bf((bf2f(uB[j]) - sm[j])*sv[j]);
        }
        *(uint4*)(hwA + ts*RS + cb) = *(const uint4*)tA;
        *(uint4*)(hwB + ts*RS + cb) = *(const uint4*)tB;
      } else {
        *(uint4*)(hwA + ts*RS + cb) = vA;
        *(uint4*)(hwB + ts*RS + cb) = vB;
      }
    }
    if(p < 1 && ldact && nA + 2 < NN){
      vA = *(const uint4*)(hIn + (size_t)(nA+2)*TIN*32 + l*8);
      vB = *(const uint4*)(hIn + (size_t)(nA+3)*TIN*32 + l*8);
    }
    bf16x8 aA0 = *(const bf16x8*)(hwA + tr*RS + quad*8);
    bf16x8 aA1 = *(const bf16x8*)(hwA + (tr+D)*RS + quad*8);
    bf16x8 aB0 = *(const bf16x8*)(hwB + tr*RS + quad*8);
    bf16x8 aB1 = *(const bf16x8*)(hwB + (tr+D)*RS + quad*8);
    f32x4 afA[2], agA[2], afB[2], agB[2];
#pragma unroll
    for(int i=0;i<2;i++){
      afA[i] = (f32x4){0.f,0.f,0.f,0.f}; agA[i] = afA[i];
      afB[i] = afA[i]; agB[i] = afA[i];
    }
#pragma unroll
    for(int i=0;i<2;i++){
      afA[i] = __builtin_amdgcn_mfma_f32_16x16x32_bf16(aA0, bwf[0][i], afA[i], 0,0,0);
      afB[i] = __builtin_amdgcn_mfma_f32_16x16x32_bf16(aB0, bwf[0][i], afB[i], 0,0,0);
      afA[i] = __builtin_amdgcn_mfma_f32_16x16x32_bf16(aA1, bwf[1][i], afA[i], 0,0,0);
      afB[i] = __builtin_amdgcn_mfma_f32_16x16x32_bf16(aB1, bwf[1][i], afB[i], 0,0,0);
      agA[i] = __builtin_amdgcn_mfma_f32_16x16x32_bf16(aA0, bwg[0][i], agA[i], 0,0,0);
      agB[i] = __builtin_amdgcn_mfma_f32_16x16x32_bf16(aB0, bwg[0][i], agB[i], 0,0,0);
      agA[i] = __builtin_amdgcn_mfma_f32_16x16x32_bf16(aA1, bwg[1][i], agA[i], 0,0,0);
      agB[i] = __builtin_amdgcn_mfma_f32_16x16x32_bf16(aB1, bwg[1][i], agB[i], 0,0,0);
    }
#pragma unroll
    for(int i=0;i<2;i++){
      int cout = 16*i + tcol;
#pragma unroll
      for(int r=0;r<4;r++){
        int t = quad*4 + r;
        if(t < TOUT){
          float fA = afA[i][r] + fbv[i];
          float gA = agA[i][r] + gbv[i];
          float fB = afB[i][r] + fbv[i];
          float gB = agB[i][r] + gbv[i];
          float gatedA = ftanh(fA)*fsig(gA);
          float gatedB = ftanh(fB)*fsig(gB);
          if(t == TOUT-1){
            gl[(size_t)nA*256 + cout] = f2bf(gatedA);
            gl[(size_t)nB*256 + cout] = f2bf(gatedB);
          }
          float oA = gatedA + bf2f(hwA[(t+D)*RS + cout]);
          float oB = gatedB + bf2f(hwB[(t+D)*RS + cout]);
          if(WRITEH){ howA[t*RS + cout] = f2bf(oA); howB[t*RS + cout] = f2bf(oB); }
          if(STATS){ sA[i] += oA + oB; s2A[i] += oA*oA + oB*oB; }
        }
      }
    }
    if(WRITEH && l < TOUT*4){
      int to = l >> 2, cb2 = (l & 3)*8;
      *(uint4*)(hOut + (size_t)nA*TOUT*32 + to*32 + cb2) = *(const uint4*)(howA + to*RS + cb2);
      *(uint4*)(hOut + (size_t)nB*TOUT*32 + to*32 + cb2) = *(const uint4*)(howB + to*RS + cb2);
    }
  }
  if(STATS){
#pragma unroll
    for(int i=0;i<2;i++){
      sA[i]  += __shfl_xor(sA[i], 16);  sA[i]  += __shfl_xor(sA[i], 32);
      s2A[i] += __shfl_xor(s2A[i], 16); s2A[i] += __shfl_xor(s2A[i], 32);
    }
    if(l < 16){
#pragma unroll
      for(int i=0;i<2;i++){
        atomicAdd(&bnred[16*i + l], sA[i]);
        atomicAdd(&bnred[32 + 16*i + l], s2A[i]);
      }
    }
    __syncthreads();
    if(tid < 64) atomicAdd(&bnOut[(blockIdx.x & 15)*64 + tid], bnred[tid]);
  }
}

// ---------------- FUSED skip GEMM + end-MLP head ----------------
__global__ __launch_bounds__(256) void k_skip_final(
    const unsigned short* __restrict__ A, const unsigned short* __restrict__ Bt,
    const float* __restrict__ bias2,
    const float* __restrict__ Wc, const float* __restrict__ bc,
    const float* __restrict__ stdev, const float* __restrict__ means,
    float* __restrict__ out){
  constexpr int LR = 40;
  constexpr int RSK = 264;
  __shared__ unsigned short pool[64*RSK];
  __shared__ float wsm[3072];
  __shared__ float bcs[12];
  unsigned short* As = pool;
  unsigned short* Bs = pool + 64*LR;
  int tid = threadIdx.x;
  int w = tid >> 6, l = tid & 63, quad = l >> 4, tcol = l & 15;
  for(int j = tid; j < 3072; j += 256){
    int c = j / 12, k = j - c*12;
    wsm[c*12 + k] = Wc[k*256 + c];
  }
  if(tid < 12) bcs[tid] = bc[tid];
  int m0 = blockIdx.x*64;
  f32x4 acc[4][4];
#pragma unroll
  for(int i = 0; i < 4; i++)
#pragma unroll
    for(int j = 0; j < 4; j++) acc[i][j] = (f32x4){0.f,0.f,0.f,0.f};
  for(int k0 = 0; k0 < 256; k0 += 32){
    int row = tid >> 2, off = (tid & 3)*8;
    uint4 a4 = *(const uint4*)(A + (size_t)(m0+row)*256 + k0 + off);
    uint4 b4[4];
#pragma unroll
    for(int it = 0; it < 4; it++){
      int idx = tid + 256*it;
      b4[it] = *(const uint4*)(Bt + (size_t)(idx>>2)*256 + k0 + (idx&3)*8);
    }
    __syncthreads();
    *(uint4*)(As + row*LR + off) = a4;
#pragma unroll
    for(int it = 0; it < 4; it++){
      int idx = tid + 256*it;
      *(uint4*)(Bs + (idx>>2)*LR + (idx&3)*8) = b4[it];
    }
    __syncthreads();
    bf16x8 av[4], bv[4];
#pragma unroll
    for(int i = 0; i < 4; i++) av[i] = *(const bf16x8*)(As + (16*i + tcol)*LR + quad*8);
#pragma unroll
    for(int j = 0; j < 4; j++) bv[j] = *(const bf16x8*)(Bs + ((w*4 + j)*16 + tcol)*LR + quad*8);
#pragma unroll
    for(int i = 0; i < 4; i++)
#pragma unroll
      for(int j = 0; j < 4; j++)
        acc[i][j] = __builtin_amdgcn_mfma_f32_16x16x32_bf16(av[i], bv[j], acc[i][j], 0, 0, 0);
  }
  __syncthreads();
#pragma unroll
  for(int i = 0; i < 4; i++)
#pragma unroll
    for(int j = 0; j < 4; j++){
      int col = (w*4 + j)*16 + tcol;
      float bb = bias2[col];
#pragma unroll
      for(int r = 0; r < 4; r++){
        int node = 16*i + quad*4 + r;
        pool[node*RSK + col] = f2bf(fmaxf(acc[i][j][r] + bb, 0.f));
      }
    }
  __syncthreads();
  int n = tid & 63, kb = (tid >> 6)*3;
  float a0 = bcs[kb], a1 = bcs[kb+1], a2 = bcs[kb+2];
  for(int c = 0; c < 256; c++){
    float s = bf2f(pool[n*RSK + c]);
    a0 += s*wsm[c*12 + kb]; a1 += s*wsm[c*12 + kb+1]; a2 += s*wsm[c*12 + kb+2];
  }
  int gn = m0 + n;
  if(gn < NN){
    float sd = stdev[gn], mn = means[gn];
    out[gn*12 + kb]   = a0*sd + mn;
    out[gn*12 + kb+1] = a1*sd + mn;
    out[gn*12 + kb+2] = a2*sd + mn;
  }
}

extern "C" void kernel_launch(void* const* d_in, const int* in_sizes, int n_in,
                              void* d_out, int out_size, void* d_ws, size_t ws_size,
                              hipStream_t stream) {
  const float* x      = (const float*)d_in[0];
  const int*   ei     = (const int*)  d_in[1];
  const float* ea     = (const float*)d_in[2];
  const float* startW = (const float*)d_in[3];
  const float* startb = (const float*)d_in[4];
  const float* fW     = (const float*)d_in[5];
  const float* fb     = (const float*)d_in[6];
  const float* gW     = (const float*)d_in[7];
  const float* gb     = (const float*)d_in[8];
  const float* sW     = (const float*)d_in[9];
  const float* sb     = (const float*)d_in[10];
  const float* g0W0   = (const float*)d_in[11];
  const float* g0W1   = (const float*)d_in[12];
  const float* g0b    = (const float*)d_in[13];
  const float* g1W0   = (const float*)d_in[14];
  const float* g1W1   = (const float*)d_in[15];
  const float* g1b    = (const float*)d_in[16];
  const float* e1W    = (const float*)d_in[17];
  const float* e1b    = (const float*)d_in[18];
  const float* e2W    = (const float*)d_in[19];
  const float* e2b    = (const float*)d_in[20];
  float* out = (float*)d_out;
  float* ws  = (float*)d_ws;

  const int MP = 20096;
  size_t o = 0;
  float* hAf = ws + o; o += (size_t)NN*208;
  float* hBf = ws + o; o += (size_t)NN*208;
  unsigned short* hA = (unsigned short*)hAf;
  unsigned short* hB = (unsigned short*)hBf;
  unsigned short* tx1   = (unsigned short*)(ws + o); o += (size_t)MP*192;
  unsigned short* glcat = (unsigned short*)(ws + o); o += (size_t)MP*128;
  unsigned short* Wt0 = (unsigned short*)(ws + o); o += 147456;
  unsigned short* Wt1 = (unsigned short*)(ws + o); o += 36864;
  unsigned short* Bwt = (unsigned short*)(ws + o); o += 32768;
  unsigned short* Wfrag = (unsigned short*)(ws + o); o += 16384;
  float* Bfrag = ws + o; o += 2048;
  float* bP0   = ws + o; o += 384;
  float* bP1   = ws + o; o += 192;
  float* bias2 = ws + o; o += 256;
  float* Wc    = ws + o; o += 3072;
  float* bc    = ws + o; o += 16;
  float* stdev = ws + o; o += NN;
  float* means = ws + o; o += NN;
  float* deg   = ws + o; o += NN;                 // deg, cnt, bnstats contiguous -> one memset
  int*   cnt   = (int*)(ws + o); o += NN;
  float* bnstats = ws + o; o += 8*1024;
  float* normb = ws + o; o += NE;
  int*   rowArr = (int*)(ws + o); o += NE;
  float* nrmArr = ws + o; o += NE;
  int*   rowptr = (int*)(ws + o); o += NN + 4;
  int*   woff   = (int*)(ws + o); o += NN;
  int*   bsum   = (int*)(ws + o); o += NBLK + 4;

  hipMemsetAsync(deg, 0, (size_t)(2*NN + 8*1024)*sizeof(float), stream);
  k_prepall<<<1836, 256, 0, stream>>>(g0W0, g0W1, g0b, g1W0, g1W1, g1b,
      sW, sb, e1W, e1b, e2W, e2b, fW, fb, gW, gb,
      Wt0, bP0, Wt1, bP1, Bwt, bias2, Wc, bc, Wfrag, Bfrag);
  k_deg<<<(NE+255)/256, 256, 0, stream>>>(ei, ea, deg);
  k_normcount<<<(NE+255)/256, 256, 0, stream>>>(ei, ea, deg, normb, cnt);
  k_scanA<<<NBLK, 256, 0, stream>>>(cnt, bsum);
  k_scanC<<<NBLK, 256, 0, stream>>>(cnt, bsum, rowptr, woff);
  k_place<<<(NE+255)/256, 256, 0, stream>>>(normb, ei, woff, rowArr, nrmArr);

  const int GB = 1280;
  // L0 fused: x -> hB, gl0, stats0
  k_fused0nb<<<500, 256, 0, stream>>>(x, startW, startb, Wfrag, Bfrag, glcat, hB,
      stdev, means, bnstats);
  // GCN0: gather (BN inline) -> tx1 ; GEMM (BN inline, n-loop inside) -> hA
  k_gather3<<<NN, 192, 0, stream>>>(hB, 384, 192, bnstats, 1.f/(NN*12.f),
      rowArr, nrmArr, rowptr, tx1);
  k_gemm_gcn<true><<<MP/128, 256, 0, stream>>>(hB, tx1, Wt0, bP0, bnstats, 1.f/(NN*12.f),
      hA, NN, 384, 384);
  // L1: hA -> hB
  k_gated5<2,12,10,false,true,true><<<GB,256,0,stream>>>(hA, hB, glcat+32,
      bnstats, bnstats+1*1024, Wfrag, Bfrag, 1, 0.f);
  // L2: hB -> hA
  k_gated5<1,10,9,true,true,true><<<GB,256,0,stream>>>(hB, hA, glcat+64,
      bnstats+1*1024, bnstats+2*1024, Wfrag, Bfrag, 2, 1.f/(NN*10.f));
  // L3: hA -> hB
  k_gated5<2,9,7,true,true,true><<<GB,256,0,stream>>>(hA, hB, glcat+96,
      bnstats+2*1024, bnstats+3*1024, Wfrag, Bfrag, 3, 1.f/(NN*9.f));
  // L4: hB -> hA
  k_gated5<1,7,6,true,true,true><<<GB,256,0,stream>>>(hB, hA, glcat+128,
      bnstats+3*1024, bnstats+4*1024, Wfrag, Bfrag, 4, 1.f/(NN*7.f));
  // GCN1: gather (BN inline on hA) -> tx1 ; GEMM (BN inline, n-loop inside) -> hB
  k_gather3<<<NN, 128, 0, stream>>>(hA, 192, 96, bnstats+4*1024, 1.f/(NN*6.f),
      rowArr, nrmArr, rowptr, tx1);
  k_gemm_gcn<true><<<MP/128, 256, 0, stream>>>(hA, tx1, Wt1, bP1, bnstats+4*1024, 1.f/(NN*6.f),
      hB, NN, 192, 192);
  // L5: hB -> hA
  k_gated5<2,6,4,false,true,true><<<GB,256,0,stream>>>(hB, hA, glcat+160,
      bnstats, bnstats+5*1024, Wfrag, Bfrag, 5, 0.f);
  // L6: hA -> hB
  k_gated5<1,4,3,true,true,true><<<GB,256,0,stream>>>(hA, hB, glcat+192,
      bnstats+5*1024, bnstats+6*1024, Wfrag, Bfrag, 6, 1.f/(NN*4.f));
  // L7: hB -> (gl only)
  k_gated5<2,3,1,true,false,false><<<GB,256,0,stream>>>(hB, nullptr, glcat+224,
      bnstats+6*1024, bnstats+7*1024, Wfrag, Bfrag, 7, 1.f/(NN*3.f));

  // fused skip GEMM + end MLP head
  k_skip_final<<<(NN+63)/64, 256, 0, stream>>>(glcat, Bwt, bias2, Wc, bc,
      stdev, means, out);
}

// Round 15
// 421.900 us; speedup vs baseline: 1.2561x; 1.2561x over previous
//
#include <hip/hip_runtime.h>
#include <math.h>

#define NN 20000
#define NE 200000
#define TT 13
#define NBLK 79   // ceil(NN/256)

typedef short bf16x8 __attribute__((ext_vector_type(8)));
typedef float f32x4 __attribute__((ext_vector_type(4)));

__device__ inline unsigned short f2bf(float f){
  union{float f; unsigned u;} v; v.f = f;
  unsigned r = v.u + 0x7fffu + ((v.u >> 16) & 1u);
  return (unsigned short)(r >> 16);
}
__device__ inline float bf2f(unsigned short h){
  union{unsigned u; float f;} v; v.u = ((unsigned)h) << 16; return v.f;
}
__device__ inline float fsig(float x){ return __builtin_amdgcn_rcpf(1.f + __expf(-x)); }
__device__ inline float ftanh(float x){ return 2.f*__builtin_amdgcn_rcpf(1.f + __expf(-2.f*x)) - 1.f; }

// ---------------- fused prep: all weight re-layouts in one dispatch ----------------
__device__ inline void d_prepw2(const float* W0, const float* W1, const float* b,
    unsigned short* Wt, float* bPerm, int F, int Kp, int T, int idx){
  if(idx >= F*Kp) return;
  int o = idx / Kp, k = idx - o*Kp;
  int to = o >> 5, co = o & 31; int fout = co*T + to;
  int ki = (k < F) ? k : k - F;
  int ti = ki >> 5, ci = ki & 31; int fin = ci*T + ti;
  float v = (k < F) ? W0[fin*F + fout] : W1[fin*F + fout];
  Wt[idx] = f2bf(v);
  if(k == 0) bPerm[o] = b[fout];
}
__device__ inline void d_prep2(const float* sW, const float* sb,
    unsigned short* Bwt, float* b2, int idx){
  if(idx >= 65536) return;
  int sOut = idx >> 8; int ic = idx & 255; int i = ic >> 5; int c = ic & 31;
  Bwt[idx] = f2bf(sW[i*8192 + sOut*32 + c]);
  if(idx < 256){
    float acc = 0.f;
    for(int ll = 0; ll < 8; ll++) acc += sb[ll*256 + idx];
    b2[idx] = acc;
  }
}
__device__ inline void d_comb(const float* e1W, const float* e1b,
    const float* e2W, const float* e2b, float* Wc, float* bc, int idx){
  if(idx >= 12*256) return;
  int k = idx >> 8, c = idx & 255;
  float acc = 0.f;
  for(int o = 0; o < 512; o++) acc += e2W[k*512+o]*e1W[o*256+c];
  Wc[idx] = acc;
  if(c == 0){
    float b = e2b[k];
    for(int o = 0; o < 512; o++) b += e2W[k*512+o]*e1b[o];
    bc[k] = b;
  }
}
__device__ inline void d_prepg(const float* fW, const float* fb,
    const float* gW, const float* gb, unsigned short* Wfrag, float* Bfrag, int idx){
  if(idx < 8*8*64*8){
    int j = idx & 7; int lane = (idx >> 3) & 63; int chunk = (idx >> 9) & 7; int layer = idx >> 12;
    int fg = chunk >> 2; int q = (chunk >> 1) & 1; int i = chunk & 1;
    int quad = lane >> 4, tcol = lane & 15;
    int cout = 16*i + tcol, cin = quad*8 + j;
    const float* W = fg ? gW : fW;
    Wfrag[idx] = f2bf(W[layer*2048 + cout*64 + cin*2 + q]);
  }
  if(idx < 8*64*4){
    int r = idx & 3; int lane = (idx >> 2) & 63; int layer = idx >> 8;
    int tcol = lane & 15;
    float v;
    if(r == 0)      v = fb[layer*32 + tcol];
    else if(r == 1) v = fb[layer*32 + 16 + tcol];
    else if(r == 2) v = gb[layer*32 + tcol];
    else            v = gb[layer*32 + 16 + tcol];
    Bfrag[idx] = v;
  }
}
__global__ __launch_bounds__(256) void k_prepall(
    const float* g0W0, const float* g0W1, const float* g0b,
    const float* g1W0, const float* g1W1, const float* g1b,
    const float* sW, const float* sb,
    const float* e1W, const float* e1b, const float* e2W, const float* e2b,
    const float* fW, const float* fb, const float* gW, const float* gb,
    unsigned short* Wt0, float* bP0, unsigned short* Wt1, float* bP1,
    unsigned short* Bwt, float* bias2, float* Wc, float* bc,
    unsigned short* Wfrag, float* Bfrag){
  int b = blockIdx.x, t = threadIdx.x;
  if(b < 1152)       d_prepw2(g0W0, g0W1, g0b, Wt0, bP0, 384, 768, 12, b*256 + t);
  else if(b < 1440)  d_prepw2(g1W0, g1W1, g1b, Wt1, bP1, 192, 384, 6, (b-1152)*256 + t);
  else if(b < 1696)  d_prep2(sW, sb, Bwt, bias2, (b-1440)*256 + t);
  else if(b < 1708)  d_comb(e1W, e1b, e2W, e2b, Wc, bc, (b-1696)*256 + t);
  else               d_prepg(fW, fb, gW, gb, Wfrag, Bfrag, (b-1708)*256 + t);
}

// ---------------- edge prep ----------------
__global__ __launch_bounds__(256) void k_deg(const int* __restrict__ ei,
    const float* __restrict__ ea, float* __restrict__ deg){
  int e = blockIdx.x*256 + threadIdx.x;
  if(e >= NE) return;
  int r = ei[e], c = ei[NE+e];
  float w = (r==c) ? 0.f : ea[e];
  if(w != 0.f) atomicAdd(&deg[r], w);
}

__global__ __launch_bounds__(256) void k_normcount(const int* __restrict__ ei,
    const float* __restrict__ ea, const float* __restrict__ deg,
    float* __restrict__ nrm, int* __restrict__ cnt){
  int e = blockIdx.x*256 + threadIdx.x;
  if(e >= NE) return;
  int r = ei[e], c = ei[NE+e];
  float w = (r==c) ? 0.f : ea[e];
  float dr = deg[r], dc = deg[c];
  float ir = (dr > 0.f) ? rsqrtf(dr) : 0.f;
  float ic = (dc > 0.f) ? rsqrtf(dc) : 0.f;
  float nv = ir*w*ic;
  nrm[e] = nv;
  if(nv != 0.f) atomicAdd(&cnt[c], 1);
}

__global__ __launch_bounds__(256) void k_scanA(const int* __restrict__ cnt, int* __restrict__ bsum){
  int i = blockIdx.x*256 + threadIdx.x;
  int l = threadIdx.x & 63, w = threadIdx.x >> 6;
  int v = (i < NN) ? cnt[i] : 0;
#pragma unroll
  for(int off = 1; off < 64; off <<= 1) v += __shfl_xor(v, off);
  __shared__ int ws4[4];
  if(l == 0) ws4[w] = v;
  __syncthreads();
  if(threadIdx.x == 0) bsum[blockIdx.x] = ws4[0]+ws4[1]+ws4[2]+ws4[3];
}

__global__ __launch_bounds__(256) void k_scanC(const int* __restrict__ cnt,
    const int* __restrict__ bsum, int* __restrict__ rowptr, int* __restrict__ woff){
  __shared__ int sb[128];
  int t = threadIdx.x;
  if(t < 128) sb[t] = (t < NBLK) ? bsum[t] : 0;
  __syncthreads();
  for(int off = 1; off < 128; off <<= 1){
    int u = 0;
    if(t < 128 && t >= off) u = sb[t-off];
    __syncthreads();
    if(t < 128) sb[t] += u;
    __syncthreads();
  }
  int i = blockIdx.x*256 + t;
  int l = t & 63, w = t >> 6;
  int v = (i < NN) ? cnt[i] : 0;
  int x = v;
#pragma unroll
  for(int off = 1; off < 64; off <<= 1){
    int u = __shfl_up(x, off);
    if(l >= off) x += u;
  }
  __shared__ int wt[4];
  if(l == 63) wt[w] = x;
  __syncthreads();
  int wo = 0;
  for(int k = 0; k < w; k++) wo += wt[k];
  int bb = (blockIdx.x > 0) ? sb[blockIdx.x-1] : 0;
  int excl = bb + wo + x - v;
  if(i < NN){ rowptr[i] = excl; woff[i] = excl; }
  if(i == 0) rowptr[NN] = sb[NBLK-1];
}

__global__ __launch_bounds__(256) void k_place(const float* __restrict__ nrm,
    const int* __restrict__ ei, int* __restrict__ woff,
    int* __restrict__ rowArr, float* __restrict__ nrmArr){
  int e = blockIdx.x*256 + threadIdx.x;
  if(e >= NE) return;
  float nv = nrm[e];
  if(nv == 0.f) return;
  int c = ei[NE+e];
  int pos = atomicAdd(&woff[c], 1);
  rowArr[pos] = ei[e];
  nrmArr[pos] = nv;
}

// ---------------- gather SpMM with INLINE BN ----------------
__global__ void k_gather3(const unsigned short* __restrict__ h, int F, int F2,
    const float* __restrict__ bnstats, float cntInv,
    const int* __restrict__ rowArr, const float* __restrict__ nrmArr,
    const int* __restrict__ rowptr, unsigned short* __restrict__ tx1){
  __shared__ float bnm[32], bnv[32];
  __shared__ int srow[64];
  __shared__ float snrm[64];
  int tid = threadIdx.x;
  if(tid < 32){
    float s = 0.f, s2 = 0.f;
#pragma unroll
    for(int b = 0; b < 16; b++){ s += bnstats[b*64 + tid]; s2 += bnstats[b*64 + 32 + tid]; }
    float m = s*cntInv; float var = s2*cntInv - m*m;
    bnm[tid] = m; bnv[tid] = rsqrtf(var + 1e-5f);
  }
  __syncthreads();
  int node = blockIdx.x;
  int f2 = tid;
  int c0 = (2*f2) & 31;
  float m0 = bnm[c0], i0 = bnv[c0], m1 = bnm[c0+1], i1 = bnv[c0+1];
  int beg = rowptr[node], end = rowptr[node+1];
  float a0 = 0.f, a1 = 0.f;
  for(int base = beg; base < end; base += 64){
    int m = end - base; if(m > 64) m = 64;
    __syncthreads();
    if(tid < m){ srow[tid] = rowArr[base+tid]; snrm[tid] = nrmArr[base+tid]; }
    __syncthreads();
    if(f2 < F2){
      for(int j = 0; j < m; j++){
        unsigned u = *(const unsigned*)(h + (size_t)srow[j]*F + 2*f2);
        float nv = snrm[j];
        a0 += nv*(bf2f((unsigned short)(u & 0xffffu)) - m0)*i0;
        a1 += nv*(bf2f((unsigned short)(u >> 16)) - m1)*i1;
      }
    }
  }
  if(f2 < F2){
    unsigned outw = (unsigned)f2bf(-a0) | ((unsigned)f2bf(-a1) << 16);
    *(unsigned*)(tx1 + (size_t)node*F + 2*f2) = outw;
  }
}

// ---------------- GCN GEMM with INLINE BN; 128 x NT tile (NT=128 or 64), 2D grid ----------------
template<int NT, bool BOUT>
__global__ __launch_bounds__(256) void k_gemm_gcn(
    const unsigned short* __restrict__ hSrc, const unsigned short* __restrict__ tx1,
    const unsigned short* __restrict__ Bt, const float* __restrict__ bias,
    const float* __restrict__ bnstats, float cntInv,
    void* __restrict__ Cv, int M, int N, int F){
  constexpr int LR = 40;
  constexpr int NFR = NT/32;            // n-frags per wave: 4 (NT=128) or 2 (NT=64)
  __shared__ unsigned short As[128*LR];
  __shared__ unsigned short Bs[NT*LR];
  __shared__ float bnm[32], bnv[32];
  int tid = threadIdx.x;
  if(tid < 32){
    float s = 0.f, s2 = 0.f;
#pragma unroll
    for(int b = 0; b < 16; b++){ s += bnstats[b*64 + tid]; s2 += bnstats[b*64 + 32 + tid]; }
    float m = s*cntInv; float var = s2*cntInv - m*m;
    bnm[tid] = m; bnv[tid] = rsqrtf(var + 1e-5f);
  }
  __syncthreads();
  int w = tid >> 6, l = tid & 63, quad = l >> 4, tcol = l & 15;
  int m0 = blockIdx.y*128, n0 = blockIdx.x*NT;
  int rw = (w & 1)*64, cw = (w >> 1)*(NT/2);
  int sr = tid >> 2, sc = (tid & 3)*8;
  float am[8], ai[8];
#pragma unroll
  for(int j = 0; j < 8; j++){ am[j] = bnm[sc+j]; ai[j] = bnv[sc+j]; }
  int K = 2*F;
  f32x4 acc[4][NFR];
#pragma unroll
  for(int i = 0; i < 4; i++)
#pragma unroll
    for(int j = 0; j < NFR; j++) acc[i][j] = (f32x4){0.f,0.f,0.f,0.f};
  for(int k0 = 0; k0 < K; k0 += 32){
    uint4 a0r, a1r;
    if(k0 < F){
      uint4 r0 = *(const uint4*)(hSrc + (size_t)(m0 + sr)*F + k0 + sc);
      uint4 r1 = *(const uint4*)(hSrc + (size_t)(m0 + 64 + sr)*F + k0 + sc);
      unsigned short o0[8], o1[8];
      const unsigned short* p0 = (const unsigned short*)&r0;
      const unsigned short* p1 = (const unsigned short*)&r1;
#pragma unroll
      for(int j = 0; j < 8; j++){
        o0[j] = f2bf((bf2f(p0[j]) - am[j])*ai[j]);
        o1[j] = f2bf((bf2f(p1[j]) - am[j])*ai[j]);
      }
      a0r = *(const uint4*)o0; a1r = *(const uint4*)o1;
    } else {
      a0r = *(const uint4*)(tx1 + (size_t)(m0 + sr)*F + (k0-F) + sc);
      a1r = *(const uint4*)(tx1 + (size_t)(m0 + 64 + sr)*F + (k0-F) + sc);
    }
    uint4 b0 = *(const uint4*)(Bt + (size_t)(n0 + sr)*K + k0 + sc);
    uint4 b1;
    if(NT == 128) b1 = *(const uint4*)(Bt + (size_t)(n0 + 64 + sr)*K + k0 + sc);
    __syncthreads();
    *(uint4*)(As + sr*LR + sc) = a0r;
    *(uint4*)(As + (64+sr)*LR + sc) = a1r;
    *(uint4*)(Bs + sr*LR + sc) = b0;
    if(NT == 128) *(uint4*)(Bs + (64+sr)*LR + sc) = b1;
    __syncthreads();
    bf16x8 av[4], bv[NFR];
#pragma unroll
    for(int i = 0; i < 4; i++) av[i] = *(const bf16x8*)(As + (rw + 16*i + tcol)*LR + quad*8);
#pragma unroll
    for(int j = 0; j < NFR; j++) bv[j] = *(const bf16x8*)(Bs + (cw + 16*j + tcol)*LR + quad*8);
#pragma unroll
    for(int i = 0; i < 4; i++)
#pragma unroll
      for(int j = 0; j < NFR; j++)
        acc[i][j] = __builtin_amdgcn_mfma_f32_16x16x32_bf16(av[i], bv[j], acc[i][j], 0, 0, 0);
  }
#pragma unroll
  for(int i = 0; i < 4; i++){
#pragma unroll
    for(int j = 0; j < NFR; j++){
      int col = n0 + cw + 16*j + tcol;
      float bb = bias[col];
#pragma unroll
      for(int r = 0; r < 4; r++){
        int row = m0 + rw + 16*i + quad*4 + r;
        if(row < M){
          float o = acc[i][j][r] + bb;
          if(BOUT) ((unsigned short*)Cv)[(size_t)row*N + col] = f2bf(o);
          else ((float*)Cv)[(size_t)row*N + col] = o;
        }
      }
    }
  }
}

// ---------------- FUSED L0: instnorm + start conv + L0 -> hB + gl + stats ----------------
__global__ __launch_bounds__(256,3) void k_fused0nb(
    const float* __restrict__ x, const float* __restrict__ startW, const float* __restrict__ startb,
    const unsigned short* __restrict__ Wfrag, const float* __restrict__ Bfrag,
    unsigned short* __restrict__ glcat, unsigned short* __restrict__ hOut,
    float* __restrict__ stdev, float* __restrict__ means,
    float* __restrict__ bnstats){
  __shared__ float xs[40][14];
  __shared__ float swl[32], sbl[32];
  __shared__ unsigned short bufB[40*12*40];
  __shared__ float bnred[64];
  int tid = threadIdx.x;
  int w = tid >> 6, l = tid & 63, quad = l >> 4, tcol = l & 15;
  int base = blockIdx.x*40;
  for(int j = tid; j < 520; j += 256){ int n = j/13, t = j - n*13; xs[n][t] = x[(size_t)(base+n)*13 + t]; }
  if(tid < 32){ swl[tid] = startW[tid]; sbl[tid] = startb[tid]; }
  if(tid < 64) bnred[tid] = 0.f;
  __syncthreads();
  if(tid < 40){
    float s = 0.f;
#pragma unroll
    for(int t = 0; t < 13; t++) s += xs[tid][t];
    float m = s*(1.0f/13.f);
    float s2 = 0.f;
#pragma unroll
    for(int t = 0; t < 13; t++){ float d = xs[tid][t]-m; s2 += d*d; }
    float sd = sqrtf(s2*(1.0f/13.f) + 1e-5f);
    float inv = 1.0f/sd;
    means[base+tid] = m; stdev[base+tid] = sd;
#pragma unroll
    for(int t = 0; t < 13; t++) xs[tid][t] = (xs[tid][t]-m)*inv;
  }
  __syncthreads();
  bf16x8 bwf[2][2], bwg[2][2];
#pragma unroll
  for(int q = 0; q < 2; q++)
#pragma unroll
    for(int i = 0; i < 2; i++){
      bwf[q][i] = *(const bf16x8*)(Wfrag + ((q*2+i)*64 + l)*8);
      bwg[q][i] = *(const bf16x8*)(Wfrag + ((4 + q*2+i)*64 + l)*8);
    }
  float4 bv4 = *(const float4*)(Bfrag + l*4);
  float fbv[2] = {bv4.x, bv4.y}, gbv[2] = {bv4.z, bv4.w};
  float sw8[8], sb8[8], swc[2], sbc[2];
#pragma unroll
  for(int j = 0; j < 8; j++){ sw8[j] = swl[quad*8+j]; sb8[j] = sbl[quad*8+j]; }
#pragma unroll
  for(int i = 0; i < 2; i++){ swc[i] = swl[16*i+tcol]; sbc[i] = sbl[16*i+tcol]; }
  float sAc[2] = {0.f,0.f}, s2Ac[2] = {0.f,0.f};
  int tr = (tcol < 12) ? tcol : 0;
  for(int p = 0; p < 5; p++){
    int slA = w*10 + 2*p, slB = slA + 1;
    float x0A = xs[slA][tr], x1A = xs[slA][tr+1];
    float x0B = xs[slB][tr], x1B = xs[slB][tr+1];
    bf16x8 aA0, aA1, aB0, aB1;
#pragma unroll
    for(int j = 0; j < 8; j++){
      aA0[j] = (short)f2bf(sw8[j]*x0A + sb8[j]);
      aA1[j] = (short)f2bf(sw8[j]*x1A + sb8[j]);
      aB0[j] = (short)f2bf(sw8[j]*x0B + sb8[j]);
      aB1[j] = (short)f2bf(sw8[j]*x1B + sb8[j]);
    }
    f32x4 afA[2], agA[2], afB[2], agB[2];
#pragma unroll
    for(int i = 0; i < 2; i++){
      afA[i] = (f32x4){0.f,0.f,0.f,0.f}; agA[i] = afA[i];
      afB[i] = afA[i]; agB[i] = afA[i];
    }
#pragma unroll
    for(int i = 0; i < 2; i++){
      afA[i] = __builtin_amdgcn_mfma_f32_16x16x32_bf16(aA0, bwf[0][i], afA[i], 0,0,0);
      afB[i] = __builtin_amdgcn_mfma_f32_16x16x32_bf16(aB0, bwf[0][i], afB[i], 0,0,0);
      afA[i] = __builtin_amdgcn_mfma_f32_16x16x32_bf16(aA1, bwf[1][i], afA[i], 0,0,0);
      afB[i] = __builtin_amdgcn_mfma_f32_16x16x32_bf16(aB1, bwf[1][i], afB[i], 0,0,0);
      agA[i] = __builtin_amdgcn_mfma_f32_16x16x32_bf16(aA0, bwg[0][i], agA[i], 0,0,0);
      agB[i] = __builtin_amdgcn_mfma_f32_16x16x32_bf16(aB0, bwg[0][i], agB[i], 0,0,0);
      agA[i] = __builtin_amdgcn_mfma_f32_16x16x32_bf16(aA1, bwg[1][i], agA[i], 0,0,0);
      agB[i] = __builtin_amdgcn_mfma_f32_16x16x32_bf16(aB1, bwg[1][i], agB[i], 0,0,0);
    }
#pragma unroll
    for(int i = 0; i < 2; i++){
      int cout = 16*i + tcol;
#pragma unroll
      for(int r = 0; r < 4; r++){
        int t = quad*4 + r;
        if(t < 12){
          float fA = afA[i][r] + fbv[i], gA = agA[i][r] + gbv[i];
          float fB = afB[i][r] + fbv[i], gB = agB[i][r] + gbv[i];
          float gatA = ftanh(fA)*fsig(gA);
          float gatB = ftanh(fB)*fsig(gB);
          if(t == 11){
            glcat[(size_t)(base+slA)*256 + cout] = f2bf(gatA);
            glcat[(size_t)(base+slB)*256 + cout] = f2bf(gatB);
          }
          float oA = gatA + swc[i]*xs[slA][t+1] + sbc[i];
          float oB = gatB + swc[i]*xs[slB][t+1] + sbc[i];
          bufB[slA*480 + t*40 + cout] = f2bf(oA);
          bufB[slB*480 + t*40 + cout] = f2bf(oB);
          sAc[i] += oA + oB; s2Ac[i] += oA*oA + oB*oB;
        }
      }
    }
  }
#pragma unroll
  for(int i = 0; i < 2; i++){
    sAc[i]  += __shfl_xor(sAc[i], 16);  sAc[i]  += __shfl_xor(sAc[i], 32);
    s2Ac[i] += __shfl_xor(s2Ac[i], 16); s2Ac[i] += __shfl_xor(s2Ac[i], 32);
  }
  if(l < 16){
#pragma unroll
    for(int i = 0; i < 2; i++){
      atomicAdd(&bnred[16*i + l], sAc[i]);
      atomicAdd(&bnred[32 + 16*i + l], s2Ac[i]);
    }
  }
  __syncthreads();
  if(tid < 64) atomicAdd(&bnstats[(blockIdx.x & 15)*64 + tid], bnred[tid]);
  for(int j = tid; j < 40*48; j += 256){
    int s = j/48; int q = j - s*48; int t = q >> 2; int cb = (q & 3)*8;
    *(uint4*)(hOut + (size_t)(base+s)*384 + t*32 + cb) = *(const uint4*)(bufB + s*480 + t*40 + cb);
  }
}

// ---------------- gated conv; wave = 4 contiguous nodes (2 pairs) ----------------
template<int D,int TIN,int TOUT,bool BNIN,bool STATS,bool WRITEH>
__global__ __launch_bounds__(256) void k_gated5(
    const unsigned short* __restrict__ hIn, unsigned short* __restrict__ hOut,
    unsigned short* __restrict__ gl,
    const float* __restrict__ bnIn, float* __restrict__ bnOut,
    const unsigned short* __restrict__ Wfrag, const float* __restrict__ Bfrag,
    int layer, float cntInv){
  constexpr int RS = 40;
  __shared__ unsigned short hs[4][2][TIN*RS];
  __shared__ unsigned short ho[4][2][WRITEH ? TOUT*RS : RS];
  __shared__ float bnm[32], bnv[32];
  __shared__ float bnred[64];
  int tid = threadIdx.x;
  int w = tid >> 6, l = tid & 63, quad = l >> 4, tcol = l & 15;
  if(BNIN && tid < 32){
    float s = 0.f, s2 = 0.f;
#pragma unroll
    for(int b = 0; b < 16; b++){ s += bnIn[b*64 + tid]; s2 += bnIn[b*64 + 32 + tid]; }
    float m = s*cntInv;
    float var = s2*cntInv - m*m;
    bnm[tid] = m; bnv[tid] = rsqrtf(var + 1e-5f);
  }
  if(STATS && tid < 64) bnred[tid] = 0.f;
  __syncthreads();
  float sm[8], sv[8];
  if(BNIN){
    int cb = (l & 3)*8;
#pragma unroll
    for(int j=0;j<8;j++){ sm[j] = bnm[cb+j]; sv[j] = bnv[cb+j]; }
  }
  const unsigned short* wfr = Wfrag + layer*4096;
  bf16x8 bwf[2][2], bwg[2][2];
#pragma unroll
  for(int q=0;q<2;q++)
#pragma unroll
    for(int i=0;i<2;i++){
      bwf[q][i] = *(const bf16x8*)(wfr + ((q*2+i)*64 + l)*8);
      bwg[q][i] = *(const bf16x8*)(wfr + ((4 + q*2+i)*64 + l)*8);
    }
  float4 bv4 = *(const float4*)(Bfrag + layer*256 + l*4);
  float fbv[2] = {bv4.x, bv4.y}, gbv[2] = {bv4.z, bv4.w};

  int tr = (tcol < TOUT) ? tcol : 0;
  unsigned short* hwA = hs[w][0];
  unsigned short* hwB = hs[w][1];
  unsigned short* howA = ho[w][0];
  unsigned short* howB = ho[w][1];
  float sA[2] = {0.f,0.f}, s2A[2] = {0.f,0.f};
  int wid = blockIdx.x*4 + w;
  int base = wid*4;
  bool ldact = (l < TIN*4);
  int ts = l >> 2, cb = (l & 3)*8;
  uint4 vA = {0,0,0,0}, vB = {0,0,0,0};
  if(ldact && base < NN){
    vA = *(const uint4*)(hIn + (size_t)base*TIN*32 + l*8);
    vB = *(const uint4*)(hIn + (size_t)(base+1)*TIN*32 + l*8);
  }
  for(int p = 0; p < 2; p++){
    int nA = base + 2*p;
    if(nA >= NN) break;
    int nB = nA + 1;
    if(ldact){
      if(BNIN){
        unsigned short tA[8], tB[8];
        const unsigned short* uA = (const unsigned short*)&vA;
        const unsigned short* uB = (const unsigned short*)&vB;
#pragma unroll
        for(int j=0;j<8;j++){
          tA[j] = f2bf((bf2f(uA[j]) - sm[j])*sv[j]);
          tB[j] = f2bf((bf2f(uB[j]) - sm[j])*sv[j]);
        }
        *(uint4*)(hwA + ts*RS + cb) = *(const uint4*)tA;
        *(uint4*)(hwB + ts*RS + cb) = *(const uint4*)tB;
      } else {
        *(uint4*)(hwA + ts*RS + cb) = vA;
        *(uint4*)(hwB + ts*RS + cb) = vB;
      }
    }
    if(p < 1 && ldact && nA + 2 < NN){
      vA = *(const uint4*)(hIn + (size_t)(nA+2)*TIN*32 + l*8);
      vB = *(const uint4*)(hIn + (size_t)(nA+3)*TIN*32 + l*8);
    }
    bf16x8 aA0 = *(const bf16x8*)(hwA + tr*RS + quad*8);
    bf16x8 aA1 = *(const bf16x8*)(hwA + (tr+D)*RS + quad*8);
    bf16x8 aB0 = *(const bf16x8*)(hwB + tr*RS + quad*8);
    bf16x8 aB1 = *(const bf16x8*)(hwB + (tr+D)*RS + quad*8);
    f32x4 afA[2], agA[2], afB[2], agB[2];
#pragma unroll
    for(int i=0;i<2;i++){
      afA[i] = (f32x4){0.f,0.f,0.f,0.f}; agA[i] = afA[i];
      afB[i] = afA[i]; agB[i] = afA[i];
    }
#pragma unroll
    for(int i=0;i<2;i++){
      afA[i] = __builtin_amdgcn_mfma_f32_16x16x32_bf16(aA0, bwf[0][i], afA[i], 0,0,0);
      afB[i] = __builtin_amdgcn_mfma_f32_16x16x32_bf16(aB0, bwf[0][i], afB[i], 0,0,0);
      afA[i] = __builtin_amdgcn_mfma_f32_16x16x32_bf16(aA1, bwf[1][i], afA[i], 0,0,0);
      afB[i] = __builtin_amdgcn_mfma_f32_16x16x32_bf16(aB1, bwf[1][i], afB[i], 0,0,0);
      agA[i] = __builtin_amdgcn_mfma_f32_16x16x32_bf16(aA0, bwg[0][i], agA[i], 0,0,0);
      agB[i] = __builtin_amdgcn_mfma_f32_16x16x32_bf16(aB0, bwg[0][i], agB[i], 0,0,0);
      agA[i] = __builtin_amdgcn_mfma_f32_16x16x32_bf16(aA1, bwg[1][i], agA[i], 0,0,0);
      agB[i] = __builtin_amdgcn_mfma_f32_16x16x32_bf16(aB1, bwg[1][i], agB[i], 0,0,0);
    }
#pragma unroll
    for(int i=0;i<2;i++){
      int cout = 16*i + tcol;
#pragma unroll
      for(int r=0;r<4;r++){
        int t = quad*4 + r;
        if(t < TOUT){
          float fA = afA[i][r] + fbv[i];
          float gA = agA[i][r] + gbv[i];
          float fB = afB[i][r] + fbv[i];
          float gB = agB[i][r] + gbv[i];
          float gatedA = ftanh(fA)*fsig(gA);
          float gatedB = ftanh(fB)*fsig(gB);
          if(t == TOUT-1){
            gl[(size_t)nA*256 + cout] = f2bf(gatedA);
            gl[(size_t)nB*256 + cout] = f2bf(gatedB);
          }
          float oA = gatedA + bf2f(hwA[(t+D)*RS + cout]);
          float oB = gatedB + bf2f(hwB[(t+D)*RS + cout]);
          if(WRITEH){ howA[t*RS + cout] = f2bf(oA); howB[t*RS + cout] = f2bf(oB); }
          if(STATS){ sA[i] += oA + oB; s2A[i] += oA*oA + oB*oB; }
        }
      }
    }
    if(WRITEH && l < TOUT*4){
      int to = l >> 2, cb2 = (l & 3)*8;
      *(uint4*)(hOut + (size_t)nA*TOUT*32 + to*32 + cb2) = *(const uint4*)(howA + to*RS + cb2);
      *(uint4*)(hOut + (size_t)nB*TOUT*32 + to*32 + cb2) = *(const uint4*)(howB + to*RS + cb2);
    }
  }
  if(STATS){
#pragma unroll
    for(int i=0;i<2;i++){
      sA[i]  += __shfl_xor(sA[i], 16);  sA[i]  += __shfl_xor(sA[i], 32);
      s2A[i] += __shfl_xor(s2A[i], 16); s2A[i] += __shfl_xor(s2A[i], 32);
    }
    if(l < 16){
#pragma unroll
      for(int i=0;i<2;i++){
        atomicAdd(&bnred[16*i + l], sA[i]);
        atomicAdd(&bnred[32 + 16*i + l], s2A[i]);
      }
    }
    __syncthreads();
    if(tid < 64) atomicAdd(&bnOut[(blockIdx.x & 15)*64 + tid], bnred[tid]);
  }
}

// ---------------- FUSED skip GEMM + end-MLP head ----------------
__global__ __launch_bounds__(256) void k_skip_final(
    const unsigned short* __restrict__ A, const unsigned short* __restrict__ Bt,
    const float* __restrict__ bias2,
    const float* __restrict__ Wc, const float* __restrict__ bc,
    const float* __restrict__ stdev, const float* __restrict__ means,
    float* __restrict__ out){
  constexpr int LR = 40;
  constexpr int RSK = 264;
  __shared__ unsigned short pool[64*RSK];
  __shared__ float wsm[3072];
  __shared__ float bcs[12];
  unsigned short* As = pool;
  unsigned short* Bs = pool + 64*LR;
  int tid = threadIdx.x;
  int w = tid >> 6, l = tid & 63, quad = l >> 4, tcol = l & 15;
  for(int j = tid; j < 3072; j += 256){
    int c = j / 12, k = j - c*12;
    wsm[c*12 + k] = Wc[k*256 + c];
  }
  if(tid < 12) bcs[tid] = bc[tid];
  int m0 = blockIdx.x*64;
  f32x4 acc[4][4];
#pragma unroll
  for(int i = 0; i < 4; i++)
#pragma unroll
    for(int j = 0; j < 4; j++) acc[i][j] = (f32x4){0.f,0.f,0.f,0.f};
  for(int k0 = 0; k0 < 256; k0 += 32){
    int row = tid >> 2, off = (tid & 3)*8;
    uint4 a4 = *(const uint4*)(A + (size_t)(m0+row)*256 + k0 + off);
    uint4 b4[4];
#pragma unroll
    for(int it = 0; it < 4; it++){
      int idx = tid + 256*it;
      b4[it] = *(const uint4*)(Bt + (size_t)(idx>>2)*256 + k0 + (idx&3)*8);
    }
    __syncthreads();
    *(uint4*)(As + row*LR + off) = a4;
#pragma unroll
    for(int it = 0; it < 4; it++){
      int idx = tid + 256*it;
      *(uint4*)(Bs + (idx>>2)*LR + (idx&3)*8) = b4[it];
    }
    __syncthreads();
    bf16x8 av[4], bv[4];
#pragma unroll
    for(int i = 0; i < 4; i++) av[i] = *(const bf16x8*)(As + (16*i + tcol)*LR + quad*8);
#pragma unroll
    for(int j = 0; j < 4; j++) bv[j] = *(const bf16x8*)(Bs + ((w*4 + j)*16 + tcol)*LR + quad*8);
#pragma unroll
    for(int i = 0; i < 4; i++)
#pragma unroll
      for(int j = 0; j < 4; j++)
        acc[i][j] = __builtin_amdgcn_mfma_f32_16x16x32_bf16(av[i], bv[j], acc[i][j], 0, 0, 0);
  }
  __syncthreads();
#pragma unroll
  for(int i = 0; i < 4; i++)
#pragma unroll
    for(int j = 0; j < 4; j++){
      int col = (w*4 + j)*16 + tcol;
      float bb = bias2[col];
#pragma unroll
      for(int r = 0; r < 4; r++){
        int node = 16*i + quad*4 + r;
        pool[node*RSK + col] = f2bf(fmaxf(acc[i][j][r] + bb, 0.f));
      }
    }
  __syncthreads();
  int n = tid & 63, kb = (tid >> 6)*3;
  float a0 = bcs[kb], a1 = bcs[kb+1], a2 = bcs[kb+2];
  for(int c = 0; c < 256; c++){
    float s = bf2f(pool[n*RSK + c]);
    a0 += s*wsm[c*12 + kb]; a1 += s*wsm[c*12 + kb+1]; a2 += s*wsm[c*12 + kb+2];
  }
  int gn = m0 + n;
  if(gn < NN){
    float sd = stdev[gn], mn = means[gn];
    out[gn*12 + kb]   = a0*sd + mn;
    out[gn*12 + kb+1] = a1*sd + mn;
    out[gn*12 + kb+2] = a2*sd + mn;
  }
}

extern "C" void kernel_launch(void* const* d_in, const int* in_sizes, int n_in,
                              void* d_out, int out_size, void* d_ws, size_t ws_size,
                              hipStream_t stream) {
  const float* x      = (const float*)d_in[0];
  const int*   ei     = (const int*)  d_in[1];
  const float* ea     = (const float*)d_in[2];
  const float* startW = (const float*)d_in[3];
  const float* startb = (const float*)d_in[4];
  const float* fW     = (const float*)d_in[5];
  const float* fb     = (const float*)d_in[6];
  const float* gW     = (const float*)d_in[7];
  const float* gb     = (const float*)d_in[8];
  const float* sW     = (const float*)d_in[9];
  const float* sb     = (const float*)d_in[10];
  const float* g0W0   = (const float*)d_in[11];
  const float* g0W1   = (const float*)d_in[12];
  const float* g0b    = (const float*)d_in[13];
  const float* g1W0   = (const float*)d_in[14];
  const float* g1W1   = (const float*)d_in[15];
  const float* g1b    = (const float*)d_in[16];
  const float* e1W    = (const float*)d_in[17];
  const float* e1b    = (const float*)d_in[18];
  const float* e2W    = (const float*)d_in[19];
  const float* e2b    = (const float*)d_in[20];
  float* out = (float*)d_out;
  float* ws  = (float*)d_ws;

  const int MP = 20096;
  size_t o = 0;
  float* hAf = ws + o; o += (size_t)NN*208;
  float* hBf = ws + o; o += (size_t)NN*208;
  unsigned short* hA = (unsigned short*)hAf;
  unsigned short* hB = (unsigned short*)hBf;
  unsigned short* tx1   = (unsigned short*)(ws + o); o += (size_t)MP*192;
  unsigned short* glcat = (unsigned short*)(ws + o); o += (size_t)MP*128;
  unsigned short* Wt0 = (unsigned short*)(ws + o); o += 147456;
  unsigned short* Wt1 = (unsigned short*)(ws + o); o += 36864;
  unsigned short* Bwt = (unsigned short*)(ws + o); o += 32768;
  unsigned short* Wfrag = (unsigned short*)(ws + o); o += 16384;
  float* Bfrag = ws + o; o += 2048;
  float* bP0   = ws + o; o += 384;
  float* bP1   = ws + o; o += 192;
  float* bias2 = ws + o; o += 256;
  float* Wc    = ws + o; o += 3072;
  float* bc    = ws + o; o += 16;
  float* stdev = ws + o; o += NN;
  float* means = ws + o; o += NN;
  float* deg   = ws + o; o += NN;                 // deg, cnt, bnstats contiguous -> one memset
  int*   cnt   = (int*)(ws + o); o += NN;
  float* bnstats = ws + o; o += 8*1024;
  float* normb = ws + o; o += NE;
  int*   rowArr = (int*)(ws + o); o += NE;
  float* nrmArr = ws + o; o += NE;
  int*   rowptr = (int*)(ws + o); o += NN + 4;
  int*   woff   = (int*)(ws + o); o += NN;
  int*   bsum   = (int*)(ws + o); o += NBLK + 4;

  hipMemsetAsync(deg, 0, (size_t)(2*NN + 8*1024)*sizeof(float), stream);
  k_prepall<<<1836, 256, 0, stream>>>(g0W0, g0W1, g0b, g1W0, g1W1, g1b,
      sW, sb, e1W, e1b, e2W, e2b, fW, fb, gW, gb,
      Wt0, bP0, Wt1, bP1, Bwt, bias2, Wc, bc, Wfrag, Bfrag);
  k_deg<<<(NE+255)/256, 256, 0, stream>>>(ei, ea, deg);
  k_normcount<<<(NE+255)/256, 256, 0, stream>>>(ei, ea, deg, normb, cnt);
  k_scanA<<<NBLK, 256, 0, stream>>>(cnt, bsum);
  k_scanC<<<NBLK, 256, 0, stream>>>(cnt, bsum, rowptr, woff);
  k_place<<<(NE+255)/256, 256, 0, stream>>>(normb, ei, woff, rowArr, nrmArr);

  const int GB = 1280;
  // L0 fused: x -> hB, gl0, stats0
  k_fused0nb<<<500, 256, 0, stream>>>(x, startW, startb, Wfrag, Bfrag, glcat, hB,
      stdev, means, bnstats);
  // GCN0: gather (BN inline) -> tx1 ; GEMM 128x128 tiles (BN inline) -> hA
  k_gather3<<<NN, 192, 0, stream>>>(hB, 384, 192, bnstats, 1.f/(NN*12.f),
      rowArr, nrmArr, rowptr, tx1);
  { dim3 g(384/128, MP/128);
    k_gemm_gcn<128,true><<<g, 256, 0, stream>>>(hB, tx1, Wt0, bP0, bnstats, 1.f/(NN*12.f),
        hA, NN, 384, 384); }
  // L1: hA -> hB
  k_gated5<2,12,10,false,true,true><<<GB,256,0,stream>>>(hA, hB, glcat+32,
      bnstats, bnstats+1*1024, Wfrag, Bfrag, 1, 0.f);
  // L2: hB -> hA
  k_gated5<1,10,9,true,true,true><<<GB,256,0,stream>>>(hB, hA, glcat+64,
      bnstats+1*1024, bnstats+2*1024, Wfrag, Bfrag, 2, 1.f/(NN*10.f));
  // L3: hA -> hB
  k_gated5<2,9,7,true,true,true><<<GB,256,0,stream>>>(hA, hB, glcat+96,
      bnstats+2*1024, bnstats+3*1024, Wfrag, Bfrag, 3, 1.f/(NN*9.f));
  // L4: hB -> hA
  k_gated5<1,7,6,true,true,true><<<GB,256,0,stream>>>(hB, hA, glcat+128,
      bnstats+3*1024, bnstats+4*1024, Wfrag, Bfrag, 4, 1.f/(NN*7.f));
  // GCN1: gather (BN inline on hA) -> tx1 ; GEMM 128x64 tiles (BN inline) -> hB
  k_gather3<<<NN, 128, 0, stream>>>(hA, 192, 96, bnstats+4*1024, 1.f/(NN*6.f),
      rowArr, nrmArr, rowptr, tx1);
  { dim3 g(192/64, MP/128);
    k_gemm_gcn<64,true><<<g, 256, 0, stream>>>(hA, tx1, Wt1, bP1, bnstats+4*1024, 1.f/(NN*6.f),
        hB, NN, 192, 192); }
  // L5: hB -> hA
  k_gated5<2,6,4,false,true,true><<<GB,256,0,stream>>>(hB, hA, glcat+160,
      bnstats, bnstats+5*1024, Wfrag, Bfrag, 5, 0.f);
  // L6: hA -> hB
  k_gated5<1,4,3,true,true,true><<<GB,256,0,stream>>>(hA, hB, glcat+192,
      bnstats+5*1024, bnstats+6*1024, Wfrag, Bfrag, 6, 1.f/(NN*4.f));
  // L7: hB -> (gl only)
  k_gated5<2,3,1,true,false,false><<<GB,256,0,stream>>>(hB, nullptr, glcat+224,
      bnstats+6*1024, bnstats+7*1024, Wfrag, Bfrag, 7, 1.f/(NN*3.f));

  // fused skip GEMM + end MLP head
  k_skip_final<<<(NN+63)/64, 256, 0, stream>>>(glcat, Bwt, bias2, Wc, bc,
      stdev, means, out);
}